// Round 8
// baseline (414.766 us; speedup 1.0000x reference)
//
#include <hip/hip_runtime.h>
#include <math.h>

#define N_NODES 20000
#define N_EDGES 200000
#define NDIM 128
#define EDIM 64
#define HDIM 256
#define HEADS 4
#define NH 1024
#define NLAYERS 3

typedef __attribute__((ext_vector_type(8))) short short8;
typedef __attribute__((ext_vector_type(4))) float floatx4;

__device__ __forceinline__ float b2f(unsigned short u) {
    union { unsigned u; float f; } c; c.u = ((unsigned)u) << 16; return c.f;
}
__device__ __forceinline__ float b2f_lo(unsigned u) {
    union { unsigned u; float f; } c; c.u = u << 16; return c.f;
}
__device__ __forceinline__ float b2f_hi(unsigned u) {
    union { unsigned u; float f; } c; c.u = u & 0xffff0000u; return c.f;
}
__device__ __forceinline__ unsigned short f2b(float f) {
    union { float f; unsigned u; } c; c.f = f;
    unsigned u = c.u;
    return (unsigned short)((u + 0x7FFFu + ((u >> 16) & 1u)) >> 16);
}
__device__ __forceinline__ float lrelu(float v) { return v > 0.f ? v : 0.2f * v; }

// ---------------- CSR scan ----------------
// single-block scan of 20000 counts -> exclusive row_ptr (+ total at [N])
__global__ __launch_bounds__(1024) void scan_full(const int* __restrict__ cnt,
                                                  int* __restrict__ row_ptr) {
    const int PER = 20;   // 1024*20 = 20480 >= 20000
    __shared__ int wtot[16];
    int t = threadIdx.x, lane = t & 63, wid = t >> 6;
    int base = t * PER;
    int loc[PER];
    int s = 0;
    #pragma unroll
    for (int i = 0; i < PER; i++) {
        int idx = base + i;
        int v = (idx < N_NODES) ? cnt[idx] : 0;
        loc[i] = s; s += v;
    }
    int inc = s;
    #pragma unroll
    for (int off = 1; off < 64; off <<= 1) {
        int tt = __shfl_up(inc, off, 64);
        if (lane >= off) inc += tt;
    }
    if (lane == 63) wtot[wid] = inc;
    __syncthreads();
    int woff = 0;
    #pragma unroll
    for (int w = 0; w < 16; w++) if (w < wid) woff += wtot[w];
    int excl = woff + inc - s;
    #pragma unroll
    for (int i = 0; i < PER; i++) {
        int idx = base + i;
        if (idx < N_NODES) row_ptr[idx] = excl + loc[i];
    }
    if (t == 1023) row_ptr[N_NODES] = excl + s;
}

// fill CSR + fused edge-weight MLP (3 layers' scalar weights) -> ewCSR4[pos]
__global__ __launch_bounds__(256) void fill_ew(const int* __restrict__ src0,
                                               const int* __restrict__ dst0,
                                               const float* __restrict__ edge_attr,
                                               const float* __restrict__ wmean3,
                                               const float* __restrict__ scal3,
                                               const int* __restrict__ row_ptr,
                                               int* __restrict__ fillc,
                                               int* __restrict__ srcCSR,
                                               float* __restrict__ ewCSR4) {
    int e = blockIdx.x * 256 + threadIdx.x;
    if (e >= N_EDGES) return;
    int d = dst0[e];
    int p = atomicAdd(&fillc[d], 1);
    int pos = row_ptr[d] + p;
    srcCSR[pos] = src0[e];
    const float* row = edge_attr + (size_t)e * EDIM;
    float s0 = 0.f, s1 = 0.f, s2 = 0.f;
    #pragma unroll
    for (int dd = 0; dd < EDIM; dd += 4) {
        float4 a  = *(const float4*)(row + dd);
        float4 w0 = *(const float4*)(wmean3 + dd);
        float4 w1 = *(const float4*)(wmean3 + 64 + dd);
        float4 w2 = *(const float4*)(wmean3 + 128 + dd);
        s0 += a.x * w0.x + a.y * w0.y + a.z * w0.z + a.w * w0.w;
        s1 += a.x * w1.x + a.y * w1.y + a.z * w1.z + a.w * w1.w;
        s2 += a.x * w2.x + a.y * w2.y + a.z * w2.z + a.w * w2.w;
    }
    *(float4*)(ewCSR4 + (size_t)pos * 4) =
        make_float4(s0 + scal3[4], s1 + scal3[12], s2 + scal3[20], 0.f);
}

// ---------------- combined prep über-kernel (all 256-thread blocks) -------------
// ranges: conv | transpose enc | gat_w_prep | ws_prep | transpose hw1 | layer_prep3
//         | edge histogram | zero a_s/a_d
#define PC_CONV   2500
#define PC_TENC   (PC_CONV + 32)
#define PC_GWP    (PC_TENC + 768)
#define PC_WSP    (PC_GWP + 12)
#define PC_THW1   (PC_WSP + 128)
#define PC_LP3    (PC_THW1 + 3)
#define PC_HIST   (PC_LP3 + 782)     // 782*256 >= 200000
#define PC_ZERO   (PC_HIST + 157)    // 157*256 >= 40000 float4s (a_s + a_d)
#define PC_TOTAL  PC_ZERO

__device__ void transpose_body(const float* in, unsigned short* out, int K, int Nn,
                               int bx, int by, float sh[32][33], float scale) {
    int tid = threadIdx.x;
    int tx = tid & 31, ty = tid >> 5;
    int kb = by * 32, nb = bx * 32;
    #pragma unroll
    for (int i = 0; i < 32; i += 8)
        sh[ty + i][tx] = in[(size_t)(kb + ty + i) * Nn + nb + tx];
    __syncthreads();
    #pragma unroll
    for (int i = 0; i < 32; i += 8)
        out[(size_t)(nb + ty + i) * K + kb + tx] = f2b(scale * sh[tx][ty + i]);
}

__global__ __launch_bounds__(256) void prep_combo(
    const float* __restrict__ node_features, unsigned short* __restrict__ nf_bf,
    const float* __restrict__ enc_w, unsigned short* __restrict__ enc_wt,
    const float* __restrict__ gat_w, unsigned short* __restrict__ gw2t,
    const float* __restrict__ att_src, const float* __restrict__ att_dst,
    float* __restrict__ ws_s, float* __restrict__ ws_d,
    const float* __restrict__ head_w1, unsigned short* __restrict__ hw1t,
    const float* __restrict__ edge_enc_w, const float* __restrict__ edge_enc_b,
    const float* __restrict__ lin_edge_w, const float* __restrict__ att_edge,
    float* __restrict__ wmean3, float* __restrict__ scal3,
    const int* __restrict__ dst0, int* __restrict__ cnt,
    float* __restrict__ a_s, float* __restrict__ a_d)
{
    __shared__ float sh[32][33];
    int b = blockIdx.x;
    int tid = threadIdx.x;
    if (b < PC_CONV) {
        int i = b * 256 + tid;
        float4 v = ((const float4*)node_features)[i];
        ushort4 o;
        o.x = f2b(v.x); o.y = f2b(v.y); o.z = f2b(v.z); o.w = f2b(v.w);
        ((ushort4*)nf_bf)[i] = o;
    } else if (b < PC_TENC) {
        int b2 = b - PC_CONV;
        transpose_body(enc_w, enc_wt, NDIM, HDIM, b2 & 7, b2 >> 3, sh, 1.f);
    } else if (b < PC_GWP) {
        int b3 = b - PC_TENC;
        int bx = b3 & 7, by = (b3 >> 3) & 7, z = b3 >> 6;
        int l = z >> 2, h = z & 3;
        const float* src = gat_w + (size_t)l * HDIM * NH + (size_t)h * HDIM;
        unsigned short* dst = gw2t + (size_t)l * HDIM * NH + (size_t)h * HDIM;
        int tx = tid & 31, ty = tid >> 5;
        int kb = by * 32, db = bx * 32;
        #pragma unroll
        for (int i = 0; i < 32; i += 8)
            sh[ty + i][tx] = src[(size_t)(kb + ty + i) * NH + db + tx];
        __syncthreads();
        #pragma unroll
        for (int i = 0; i < 32; i += 8)
            dst[(size_t)(db + ty + i) * NH + kb + tx] = f2b(0.25f * sh[tx][ty + i]);
    } else if (b < PC_WSP) {
        int bx = b - PC_GWP;
        int l = bx >> 2, h = bx & 3;
        int k = tid;
        const float* wrow = gat_w + (size_t)l * HDIM * NH + (size_t)k * NH + h * HDIM;
        const float* as = att_src + (size_t)l * NH + h * HDIM;
        const float* ad = att_dst + (size_t)l * NH + h * HDIM;
        float s1 = 0.f, s2 = 0.f;
        for (int d = 0; d < HDIM; d += 4) {
            float4 w4 = *(const float4*)(wrow + d);
            float4 a4 = *(const float4*)(as + d);
            float4 b4 = *(const float4*)(ad + d);
            s1 += w4.x * a4.x + w4.y * a4.y + w4.z * a4.z + w4.w * a4.w;
            s2 += w4.x * b4.x + w4.y * b4.y + w4.z * b4.z + w4.w * b4.w;
        }
        ws_s[(size_t)bx * HDIM + k] = s1;
        ws_d[(size_t)bx * HDIM + k] = s2;
    } else if (b < PC_THW1) {
        int b4 = b - PC_WSP;
        int bx = b4 & 3, by = (b4 >> 2) & 7, z = b4 >> 5;
        transpose_body(head_w1 + (size_t)z * HDIM * 128,
                       hw1t + (size_t)z * 128 * HDIM, HDIM, 128, bx, by, sh, 1.f);
    } else if (b < PC_LP3) {
        int l = b - PC_THW1;
        const float* eew = edge_enc_w + (size_t)l * EDIM * HDIM;
        const float* eeb = edge_enc_b + (size_t)l * HDIM;
        const float* lew = lin_edge_w + (size_t)l * NH;
        const float* ae  = att_edge + (size_t)l * NH;
        float* wm = wmean3 + l * 64;
        float* sc = scal3 + l * 8;
        if (tid < 64) {
            float s = 0.f;
            for (int d = 0; d < HDIM; d++) s += eew[tid * HDIM + d];
            wm[tid] = s * (1.f / HDIM);
        } else if (tid < 68) {
            int h = tid - 64;
            float s = 0.f;
            for (int d = 0; d < HDIM; d++) s += lew[h * HDIM + d] * ae[h * HDIM + d];
            sc[h] = s;
        } else if (tid == 68) {
            float s = 0.f;
            for (int d = 0; d < HDIM; d++) s += eeb[d];
            sc[4] = s * (1.f / HDIM);
        }
    } else if (b < PC_HIST) {
        int e = (b - PC_LP3) * 256 + tid;
        if (e < N_EDGES) atomicAdd(&cnt[dst0[e]], 1);
    } else {
        int idx = (b - PC_HIST) * 256 + tid;
        if (idx < 2 * N_NODES) {
            float4 z = make_float4(0.f, 0.f, 0.f, 0.f);
            if (idx < N_NODES) ((float4*)a_s)[idx] = z;
            else ((float4*)a_d)[idx - N_NODES] = z;
        }
    }
}

// ---------------- bf16 MFMA GEMM: BM=64, BN=128, BK=64, XCD-grouped grid --------
// ATTN: epilogue computes partial layer-0 attn dots over this block's 128 cols
// from the bf16-rounded Cs tile and atomicAdds into a_s/a_d (zeroed in prep).
template <bool RELU, bool BIAS, bool ATTN>
__global__ __launch_bounds__(256) void gemm_bf16(
    const unsigned short* __restrict__ A, const unsigned short* __restrict__ Bt,
    const float* __restrict__ bias, unsigned short* __restrict__ C,
    int M, int Ntot, int K,
    const float* __restrict__ ws_s = nullptr, const float* __restrict__ ws_d = nullptr,
    float* __restrict__ a_s = nullptr, float* __restrict__ a_d = nullptr)
{
    __shared__ char lds[24576];
    unsigned short* As = (unsigned short*)lds;            // 2 planes of 64x32 (8 KB)
    unsigned short* Bs = (unsigned short*)(lds + 8192);   // 2 planes of 128x32 (16 KB)
    unsigned short* Cs = (unsigned short*)lds;            // 64 x 128 bf16 epilogue

    int Cb = Ntot >> 7;
    int P  = (M + 63) >> 6;
    int d  = blockIdx.x;
    int xcd = d & 7;
    int i5  = d >> 3;
    int p   = xcd + 8 * (i5 / Cb);
    int cblk = i5 % Cb;
    if (p >= P) return;
    int row0 = p * 64;
    int col0 = cblk * 128;

    int tid = threadIdx.x;
    int lane = tid & 63;
    int wid = tid >> 6;
    int wm = (wid >> 1) * 32;
    int wn = (wid & 1) * 64;
    int lm = lane & 15;
    int q8 = (lane >> 4) * 8;
    int q4 = (lane >> 4) * 4;

    floatx4 acc[2][4];
    #pragma unroll
    for (int i = 0; i < 2; i++)
        #pragma unroll
        for (int j = 0; j < 4; j++)
            acc[i][j] = (floatx4)(0.f);

    int arow = tid >> 2;
    int acol = (tid & 3) * 8;
    int garow = row0 + arow; if (garow > M - 1) garow = M - 1;

    for (int k0 = 0; k0 < K; k0 += 64) {
        #pragma unroll
        for (int kk = 0; kk < 2; kk++) {
            int kb = k0 + kk * 32;
            __builtin_amdgcn_global_load_lds(
                (__attribute__((address_space(1))) const void*)(A + (size_t)garow * K + kb + acol),
                (__attribute__((address_space(3))) void*)(As + kk * 2048 + tid * 8), 16, 0, 0);
            #pragma unroll
            for (int r = 0; r < 2; r++) {
                int chunk = tid + r * 256;
                int brow = chunk >> 2;
                int bcol = (chunk & 3) * 8;
                __builtin_amdgcn_global_load_lds(
                    (__attribute__((address_space(1))) const void*)(Bt + (size_t)(col0 + brow) * K + kb + bcol),
                    (__attribute__((address_space(3))) void*)(Bs + kk * 4096 + chunk * 8), 16, 0, 0);
            }
        }
        __syncthreads();
        #pragma unroll
        for (int kk = 0; kk < 2; kk++) {
            short8 af[2], bf[4];
            #pragma unroll
            for (int i = 0; i < 2; i++)
                af[i] = *(const short8*)(As + kk * 2048 + (wm + i * 16 + lm) * 32 + q8);
            #pragma unroll
            for (int j = 0; j < 4; j++)
                bf[j] = *(const short8*)(Bs + kk * 4096 + (wn + j * 16 + lm) * 32 + q8);
            #pragma unroll
            for (int i = 0; i < 2; i++)
                #pragma unroll
                for (int j = 0; j < 4; j++)
                    acc[i][j] = __builtin_amdgcn_mfma_f32_16x16x32_bf16(af[i], bf[j], acc[i][j], 0, 0, 0);
        }
        __syncthreads();
    }

    #pragma unroll
    for (int i = 0; i < 2; i++) {
        #pragma unroll
        for (int j = 0; j < 4; j++) {
            int cl = wn + j * 16 + lm;
            float bv = BIAS ? bias[col0 + cl] : 0.f;
            #pragma unroll
            for (int reg = 0; reg < 4; reg++) {
                int rl = wm + i * 16 + q4 + reg;
                float v = acc[i][j][reg];
                if (BIAS) v += bv;
                if (RELU) v = fmaxf(v, 0.f);
                Cs[rl * 128 + cl] = f2b(v);
            }
        }
    }
    __syncthreads();
    int row = tid >> 2;
    int seg = (tid & 3) * 32;
    if (row0 + row < M) {
        int4 vv[4];
        #pragma unroll
        for (int u = 0; u < 4; u++) {
            vv[u] = *(const int4*)(Cs + row * 128 + seg + u * 8);
            *(int4*)(C + (size_t)(row0 + row) * Ntot + col0 + seg + u * 8) = vv[u];
        }
        if (ATTN) {
            float ss[4], sd[4];
            #pragma unroll
            for (int h = 0; h < 4; h++) { ss[h] = 0.f; sd[h] = 0.f; }
            #pragma unroll
            for (int u = 0; u < 4; u++) {
                float x0 = b2f_lo((unsigned)vv[u].x), x1 = b2f_hi((unsigned)vv[u].x);
                float x2 = b2f_lo((unsigned)vv[u].y), x3 = b2f_hi((unsigned)vv[u].y);
                float x4 = b2f_lo((unsigned)vv[u].z), x5 = b2f_hi((unsigned)vv[u].z);
                float x6 = b2f_lo((unsigned)vv[u].w), x7 = b2f_hi((unsigned)vv[u].w);
                int cg = col0 + seg + u * 8;
                #pragma unroll
                for (int h = 0; h < 4; h++) {
                    float4 w0 = *(const float4*)(ws_s + h * HDIM + cg);
                    float4 w1 = *(const float4*)(ws_s + h * HDIM + cg + 4);
                    ss[h] += x0 * w0.x + x1 * w0.y + x2 * w0.z + x3 * w0.w
                           + x4 * w1.x + x5 * w1.y + x6 * w1.z + x7 * w1.w;
                    float4 d0 = *(const float4*)(ws_d + h * HDIM + cg);
                    float4 d1 = *(const float4*)(ws_d + h * HDIM + cg + 4);
                    sd[h] += x0 * d0.x + x1 * d0.y + x2 * d0.z + x3 * d0.w
                           + x4 * d1.x + x5 * d1.y + x6 * d1.z + x7 * d1.w;
                }
            }
            #pragma unroll
            for (int h = 0; h < 4; h++) {
                ss[h] += __shfl_xor(ss[h], 1, 64);
                ss[h] += __shfl_xor(ss[h], 2, 64);
                sd[h] += __shfl_xor(sd[h], 1, 64);
                sd[h] += __shfl_xor(sd[h], 2, 64);
            }
            if ((tid & 3) == 0) {
                int n = row0 + row;
                #pragma unroll
                for (int h = 0; h < 4; h++) {
                    atomicAdd(&a_s[n * 4 + h], ss[h]);
                    atomicAdd(&a_d[n * 4 + h], sd[h]);
                }
            }
        }
    }
}

// ---------------- head GEMM (BM=64, BN=128, BK=64) + fused per-head [128->1] ----
__global__ __launch_bounds__(256) void gemm_head(
    const unsigned short* __restrict__ A, const unsigned short* __restrict__ Bt,
    const float* __restrict__ bias, int M, int Ntot, int K,
    const float* __restrict__ w2, const float* __restrict__ b2v,
    float* __restrict__ outp)
{
    __shared__ char lds[24576];
    unsigned short* As = (unsigned short*)lds;
    unsigned short* Bs = (unsigned short*)(lds + 8192);
    unsigned short* Cs = (unsigned short*)lds;

    int Cb = Ntot >> 7;
    int P  = (M + 63) >> 6;
    int d  = blockIdx.x;
    int xcd = d & 7;
    int i5  = d >> 3;
    int p   = xcd + 8 * (i5 / Cb);
    int cblk = i5 % Cb;
    if (p >= P) return;
    int row0 = p * 64;
    int col0 = cblk * 128;

    int tid = threadIdx.x;
    int lane = tid & 63;
    int wid = tid >> 6;
    int wm = (wid >> 1) * 32;
    int wn = (wid & 1) * 64;
    int lm = lane & 15;
    int q8 = (lane >> 4) * 8;
    int q4 = (lane >> 4) * 4;

    floatx4 acc[2][4];
    #pragma unroll
    for (int i = 0; i < 2; i++)
        #pragma unroll
        for (int j = 0; j < 4; j++)
            acc[i][j] = (floatx4)(0.f);

    int arow = tid >> 2;
    int acol = (tid & 3) * 8;
    int garow = row0 + arow; if (garow > M - 1) garow = M - 1;

    for (int k0 = 0; k0 < K; k0 += 64) {
        #pragma unroll
        for (int kk = 0; kk < 2; kk++) {
            int kb = k0 + kk * 32;
            __builtin_amdgcn_global_load_lds(
                (__attribute__((address_space(1))) const void*)(A + (size_t)garow * K + kb + acol),
                (__attribute__((address_space(3))) void*)(As + kk * 2048 + tid * 8), 16, 0, 0);
            #pragma unroll
            for (int r = 0; r < 2; r++) {
                int chunk = tid + r * 256;
                int brow = chunk >> 2;
                int bcol = (chunk & 3) * 8;
                __builtin_amdgcn_global_load_lds(
                    (__attribute__((address_space(1))) const void*)(Bt + (size_t)(col0 + brow) * K + kb + bcol),
                    (__attribute__((address_space(3))) void*)(Bs + kk * 4096 + chunk * 8), 16, 0, 0);
            }
        }
        __syncthreads();
        #pragma unroll
        for (int kk = 0; kk < 2; kk++) {
            short8 af[2], bf[4];
            #pragma unroll
            for (int i = 0; i < 2; i++)
                af[i] = *(const short8*)(As + kk * 2048 + (wm + i * 16 + lm) * 32 + q8);
            #pragma unroll
            for (int j = 0; j < 4; j++)
                bf[j] = *(const short8*)(Bs + kk * 4096 + (wn + j * 16 + lm) * 32 + q8);
            #pragma unroll
            for (int i = 0; i < 2; i++)
                #pragma unroll
                for (int j = 0; j < 4; j++)
                    acc[i][j] = __builtin_amdgcn_mfma_f32_16x16x32_bf16(af[i], bf[j], acc[i][j], 0, 0, 0);
        }
        __syncthreads();
    }

    #pragma unroll
    for (int i = 0; i < 2; i++) {
        #pragma unroll
        for (int j = 0; j < 4; j++) {
            int cl = wn + j * 16 + lm;
            float bv = bias[col0 + cl];
            #pragma unroll
            for (int reg = 0; reg < 4; reg++) {
                int rl = wm + i * 16 + q4 + reg;
                float v = fmaxf(acc[i][j][reg] + bv, 0.f);
                Cs[rl * 128 + cl] = f2b(v);
            }
        }
    }
    __syncthreads();
    int row = tid >> 2;
    int seg = (tid & 3) * 32;
    int k = col0 >> 7;
    const float* wr = w2 + k * 128;
    const unsigned short* cr = Cs + row * 128 + seg;
    float s = 0.f;
    #pragma unroll
    for (int u = 0; u < 4; u++) {
        int4 v = *(const int4*)(cr + u * 8);
        float4 w0 = *(const float4*)(wr + seg + u * 8);
        float4 w1 = *(const float4*)(wr + seg + u * 8 + 4);
        s += b2f_lo((unsigned)v.x) * w0.x + b2f_hi((unsigned)v.x) * w0.y
           + b2f_lo((unsigned)v.y) * w0.z + b2f_hi((unsigned)v.y) * w0.w;
        s += b2f_lo((unsigned)v.z) * w1.x + b2f_hi((unsigned)v.z) * w1.y
           + b2f_lo((unsigned)v.w) * w1.z + b2f_hi((unsigned)v.w) * w1.w;
    }
    s += __shfl_xor(s, 1, 64);
    s += __shfl_xor(s, 2, 64);
    if ((tid & 3) == 0 && row0 + row < M) {
        s += b2v[k];
        if (k == 0 || k == 3) s = 1.f / (1.f + __expf(-s));
        outp[(size_t)k * N_NODES + row0 + row] = s;
    }
}

// Fused edge-logits + softmax + aggregate + in-wave self-loop weight.
// TWO nodes per wave (half-wave of 32 lanes, 16 B/lane gathers -> each
// global_load_dwordx4 fetches 1 KB = two x-rows). 8 nodes/block.
// ALL accumulators are named floatx4 registers - no arrays, no spill.
__global__ __launch_bounds__(256) void gat_agg_fused(
    const unsigned short* __restrict__ x_bf, const float* __restrict__ a_s,
    const float* __restrict__ a_d,
    const float* __restrict__ scal, const int* __restrict__ row_ptr,
    const int* __restrict__ srcCSR, const float* __restrict__ ewCSR4,
    int l, unsigned short* __restrict__ agg)
{
    int sub = threadIdx.x & 31;
    int hw  = threadIdx.x >> 5;               // half-wave id 0..7
    int n = blockIdx.x * 8 + hw;
    int r0 = row_ptr[n];
    int deg = row_ptr[n + 1] - r0;
    int cnt = deg + 1;
    int cntMax = max(cnt, __shfl_xor(cnt, 32, 64));   // wave-uniform bound

    float4 c4 = *(const float4*)scal;
    float4 as4 = *(const float4*)(a_s + (size_t)n * 4);
    float4 ad4 = *(const float4*)(a_d + (size_t)n * 4);

    // chunk-0 edge data in registers; row-sum of w for the self-loop weight
    int sv0 = n; float w0 = 0.f;
    if (sub < deg) {
        sv0 = srcCSR[r0 + sub];
        w0 = ewCSR4[(((size_t)(r0 + sub)) << 2) + l];
    }
    float sw = w0;
    for (int i = 32 + sub; i < deg; i += 32)
        sw += ewCSR4[(((size_t)(r0 + i)) << 2) + l];
    #pragma unroll
    for (int off = 16; off > 0; off >>= 1) sw += __shfl_xor(sw, off, 32);
    float lw = sw / fmaxf((float)deg, 1.f);

    float4 zself;
    zself.x = lrelu(as4.x + ad4.x + c4.x * lw);
    zself.y = lrelu(as4.y + ad4.y + c4.y * lw);
    zself.z = lrelu(as4.z + ad4.z + c4.z * lw);
    zself.w = lrelu(as4.w + ad4.w + c4.w * lw);

    auto comp_z = [&](int c0, int& sv, float4& z) {
        int ix = c0 + sub;
        if (ix < deg) {
            sv = srcCSR[r0 + ix];
            float w = ewCSR4[(((size_t)(r0 + ix)) << 2) + l];
            float4 zs = *(const float4*)(a_s + (size_t)sv * 4);
            z.x = lrelu(zs.x + ad4.x + c4.x * w);
            z.y = lrelu(zs.y + ad4.y + c4.y * w);
            z.z = lrelu(zs.z + ad4.z + c4.z * w);
            z.w = lrelu(zs.w + ad4.w + c4.w * w);
        } else if (ix == deg) {
            sv = n; z = zself;
        } else {
            sv = n; z.x = z.y = z.z = z.w = -1e30f;
        }
    };

    float4 z0;
    if (sub < deg) {
        float4 zs = *(const float4*)(a_s + (size_t)sv0 * 4);
        z0.x = lrelu(zs.x + ad4.x + c4.x * w0);
        z0.y = lrelu(zs.y + ad4.y + c4.y * w0);
        z0.z = lrelu(zs.z + ad4.z + c4.z * w0);
        z0.w = lrelu(zs.w + ad4.w + c4.w * w0);
    } else if (sub == deg) {
        z0 = zself;
    } else {
        z0.x = z0.y = z0.z = z0.w = -1e30f;
    }

    // no max-subtraction: logits O(1-3) here (softmax shift-invariant, f32-exact)
    float4 p0;
    p0.x = __expf(z0.x); p0.y = __expf(z0.y);
    p0.z = __expf(z0.z); p0.w = __expf(z0.w);
    float s0 = p0.x, s1 = p0.y, s2 = p0.z, s3 = p0.w;
    for (int c0 = 32; c0 < cnt; c0 += 32) {     // no shfl inside: per-half bound ok
        int sv; float4 z; comp_z(c0, sv, z);
        s0 += __expf(z.x); s1 += __expf(z.y);
        s2 += __expf(z.z); s3 += __expf(z.w);
    }
    #pragma unroll
    for (int off = 16; off > 0; off >>= 1) {
        s0 += __shfl_xor(s0, off, 32);
        s1 += __shfl_xor(s1, off, 32);
        s2 += __shfl_xor(s2, off, 32);
        s3 += __shfl_xor(s3, off, 32);
    }
    float i0 = 1.f / s0, i1 = 1.f / s1, i2 = 1.f / s2, i3 = 1.f / s3;
    float4 al0;
    al0.x = p0.x * i0; al0.y = p0.y * i1; al0.z = p0.z * i2; al0.w = p0.w * i3;

    // 8 named vector accumulators (4 heads x {lo,hi} halves of this lane's 8 dims)
    floatx4 acc0l = (floatx4)(0.f), acc0h = (floatx4)(0.f);
    floatx4 acc1l = (floatx4)(0.f), acc1h = (floatx4)(0.f);
    floatx4 acc2l = (floatx4)(0.f), acc2h = (floatx4)(0.f);
    floatx4 acc3l = (floatx4)(0.f), acc3h = (floatx4)(0.f);
    const unsigned short* xw = x_bf + (size_t)sub * 8;

    auto acc_one = [&](uint4 u, float a0, float a1, float a2, float a3) {
        floatx4 xl, xh;
        xl[0] = b2f_lo(u.x); xl[1] = b2f_hi(u.x);
        xl[2] = b2f_lo(u.y); xl[3] = b2f_hi(u.y);
        xh[0] = b2f_lo(u.z); xh[1] = b2f_hi(u.z);
        xh[2] = b2f_lo(u.w); xh[3] = b2f_hi(u.w);
        acc0l += xl * a0; acc0h += xh * a0;
        acc1l += xl * a1; acc1h += xh * a1;
        acc2l += xl * a2; acc2h += xh * a2;
        acc3l += xl * a3; acc3h += xh * a3;
    };

    auto agg_chunk = [&](int sv, float4 al, int mc) {   // mc is wave-uniform
        int j = 0;
        for (; j + 3 < mc; j += 4) {
            int sA = __shfl(sv, j, 32);
            int sB = __shfl(sv, j + 1, 32);
            int sC = __shfl(sv, j + 2, 32);
            int sD = __shfl(sv, j + 3, 32);
            uint4 uA = *(const uint4*)(xw + (size_t)sA * HDIM);
            uint4 uB = *(const uint4*)(xw + (size_t)sB * HDIM);
            uint4 uC = *(const uint4*)(xw + (size_t)sC * HDIM);
            uint4 uD = *(const uint4*)(xw + (size_t)sD * HDIM);
            acc_one(uA, __shfl(al.x, j, 32), __shfl(al.y, j, 32),
                        __shfl(al.z, j, 32), __shfl(al.w, j, 32));
            acc_one(uB, __shfl(al.x, j + 1, 32), __shfl(al.y, j + 1, 32),
                        __shfl(al.z, j + 1, 32), __shfl(al.w, j + 1, 32));
            acc_one(uC, __shfl(al.x, j + 2, 32), __shfl(al.y, j + 2, 32),
                        __shfl(al.z, j + 2, 32), __shfl(al.w, j + 2, 32));
            acc_one(uD, __shfl(al.x, j + 3, 32), __shfl(al.y, j + 3, 32),
                        __shfl(al.z, j + 3, 32), __shfl(al.w, j + 3, 32));
        }
        for (; j + 1 < mc; j += 2) {
            int sA = __shfl(sv, j, 32);
            int sB = __shfl(sv, j + 1, 32);
            uint4 uA = *(const uint4*)(xw + (size_t)sA * HDIM);
            uint4 uB = *(const uint4*)(xw + (size_t)sB * HDIM);
            acc_one(uA, __shfl(al.x, j, 32), __shfl(al.y, j, 32),
                        __shfl(al.z, j, 32), __shfl(al.w, j, 32));
            acc_one(uB, __shfl(al.x, j + 1, 32), __shfl(al.y, j + 1, 32),
                        __shfl(al.z, j + 1, 32), __shfl(al.w, j + 1, 32));
        }
        if (j < mc) {
            int sA = __shfl(sv, j, 32);
            uint4 uA = *(const uint4*)(xw + (size_t)sA * HDIM);
            acc_one(uA, __shfl(al.x, j, 32), __shfl(al.y, j, 32),
                        __shfl(al.z, j, 32), __shfl(al.w, j, 32));
        }
    };

    agg_chunk(sv0, al0, min(32, cntMax));
    for (int c0 = 32; c0 < cntMax; c0 += 32) {          // uniform bound (shfl inside)
        int sv; float4 z; comp_z(c0, sv, z);
        float4 al;
        al.x = __expf(z.x) * i0; al.y = __expf(z.y) * i1;
        al.z = __expf(z.z) * i2; al.w = __expf(z.w) * i3;
        agg_chunk(sv, al, min(32, cntMax - c0));
    }

    unsigned short* ag = agg + (size_t)n * NH + sub * 8;
    {
        uint4 o;
        o.x = (unsigned)f2b(acc0l[0]) | ((unsigned)f2b(acc0l[1]) << 16);
        o.y = (unsigned)f2b(acc0l[2]) | ((unsigned)f2b(acc0l[3]) << 16);
        o.z = (unsigned)f2b(acc0h[0]) | ((unsigned)f2b(acc0h[1]) << 16);
        o.w = (unsigned)f2b(acc0h[2]) | ((unsigned)f2b(acc0h[3]) << 16);
        *(uint4*)(ag + 0 * 256) = o;
    }
    {
        uint4 o;
        o.x = (unsigned)f2b(acc1l[0]) | ((unsigned)f2b(acc1l[1]) << 16);
        o.y = (unsigned)f2b(acc1l[2]) | ((unsigned)f2b(acc1l[3]) << 16);
        o.z = (unsigned)f2b(acc1h[0]) | ((unsigned)f2b(acc1h[1]) << 16);
        o.w = (unsigned)f2b(acc1h[2]) | ((unsigned)f2b(acc1h[3]) << 16);
        *(uint4*)(ag + 1 * 256) = o;
    }
    {
        uint4 o;
        o.x = (unsigned)f2b(acc2l[0]) | ((unsigned)f2b(acc2l[1]) << 16);
        o.y = (unsigned)f2b(acc2l[2]) | ((unsigned)f2b(acc2l[3]) << 16);
        o.z = (unsigned)f2b(acc2h[0]) | ((unsigned)f2b(acc2h[1]) << 16);
        o.w = (unsigned)f2b(acc2h[2]) | ((unsigned)f2b(acc2h[3]) << 16);
        *(uint4*)(ag + 2 * 256) = o;
    }
    {
        uint4 o;
        o.x = (unsigned)f2b(acc3l[0]) | ((unsigned)f2b(acc3l[1]) << 16);
        o.y = (unsigned)f2b(acc3l[2]) | ((unsigned)f2b(acc3l[3]) << 16);
        o.z = (unsigned)f2b(acc3h[0]) | ((unsigned)f2b(acc3h[1]) << 16);
        o.w = (unsigned)f2b(acc3h[2]) | ((unsigned)f2b(acc3h[3]) << 16);
        *(uint4*)(ag + 3 * 256) = o;
    }
}

// LN(y) + residual ReLU, in-place x. One wave per node.
template <bool ATTN, bool EMB>
__global__ __launch_bounds__(256) void ln_residual(const unsigned short* __restrict__ y_bf,
                                                   const float* __restrict__ ln_g,
                                                   const float* __restrict__ ln_b,
                                                   unsigned short* __restrict__ x_bf,
                                                   const float* __restrict__ ws_s,
                                                   const float* __restrict__ ws_d,
                                                   float* __restrict__ a_s,
                                                   float* __restrict__ a_d,
                                                   float* __restrict__ emb_out)
{
    int n = blockIdx.x * 4 + (threadIdx.x >> 6);
    int lane = threadIdx.x & 63;
    ushort4 yv = *(const ushort4*)(y_bf + (size_t)n * HDIM + lane * 4);
    float y0 = b2f(yv.x), y1 = b2f(yv.y), y2 = b2f(yv.z), y3 = b2f(yv.w);
    float s1 = y0 + y1 + y2 + y3;
    float s2 = y0 * y0 + y1 * y1 + y2 * y2 + y3 * y3;
    #pragma unroll
    for (int off = 32; off > 0; off >>= 1) {
        s1 += __shfl_xor(s1, off, 64);
        s2 += __shfl_xor(s2, off, 64);
    }
    float mu = s1 * (1.f / HDIM);
    float var = s2 * (1.f / HDIM) - mu * mu;
    float rsig = rsqrtf(var + 1e-5f);
    float4 g = *(const float4*)(ln_g + lane * 4);
    float4 b = *(const float4*)(ln_b + lane * 4);
    ushort4 xv = *(const ushort4*)(x_bf + (size_t)n * HDIM + lane * 4);
    ushort4 o;
    o.x = f2b(fmaxf(b2f(xv.x) + g.x * (y0 - mu) * rsig + b.x, 0.f));
    o.y = f2b(fmaxf(b2f(xv.y) + g.y * (y1 - mu) * rsig + b.y, 0.f));
    o.z = f2b(fmaxf(b2f(xv.z) + g.z * (y2 - mu) * rsig + b.z, 0.f));
    o.w = f2b(fmaxf(b2f(xv.w) + g.w * (y3 - mu) * rsig + b.w, 0.f));
    *(ushort4*)(x_bf + (size_t)n * HDIM + lane * 4) = o;

    float xn0 = b2f(o.x), xn1 = b2f(o.y), xn2 = b2f(o.z), xn3 = b2f(o.w);
    if (EMB) {
        *(float4*)(emb_out + (size_t)n * HDIM + lane * 4) = make_float4(xn0, xn1, xn2, xn3);
    }
    if (ATTN) {
        float ss[4], sd[4];
        #pragma unroll
        for (int h = 0; h < 4; h++) {
            float4 s4 = *(const float4*)(ws_s + h * HDIM + lane * 4);
            float4 d4 = *(const float4*)(ws_d + h * HDIM + lane * 4);
            ss[h] = xn0 * s4.x + xn1 * s4.y + xn2 * s4.z + xn3 * s4.w;
            sd[h] = xn0 * d4.x + xn1 * d4.y + xn2 * d4.z + xn3 * d4.w;
        }
        #pragma unroll
        for (int off = 32; off > 0; off >>= 1)
            #pragma unroll
            for (int h = 0; h < 4; h++) {
                ss[h] += __shfl_xor(ss[h], off, 64);
                sd[h] += __shfl_xor(sd[h], off, 64);
            }
        if (lane == 0) {
            *(float4*)(a_s + n * 4) = make_float4(ss[0], ss[1], ss[2], ss[3]);
            *(float4*)(a_d + n * 4) = make_float4(sd[0], sd[1], sd[2], sd[3]);
        }
    }
}

extern "C" void kernel_launch(void* const* d_in, const int* in_sizes, int n_in,
                              void* d_out, int out_size, void* d_ws, size_t ws_size,
                              hipStream_t stream) {
    const float* node_features = (const float*)d_in[0];
    const float* edge_attr     = (const float*)d_in[1];
    const float* enc_w         = (const float*)d_in[2];
    const float* enc_b         = (const float*)d_in[3];
    const float* edge_enc_w    = (const float*)d_in[4];
    const float* edge_enc_b    = (const float*)d_in[5];
    const float* gat_w         = (const float*)d_in[6];
    const float* att_src       = (const float*)d_in[7];
    const float* att_dst       = (const float*)d_in[8];
    const float* att_edge      = (const float*)d_in[9];
    const float* lin_edge_w    = (const float*)d_in[10];
    const float* gat_b         = (const float*)d_in[11];
    const float* ln_g          = (const float*)d_in[12];
    const float* ln_b          = (const float*)d_in[13];
    const float* head_w1       = (const float*)d_in[14];
    const float* head_b1       = (const float*)d_in[15];
    const float* head_w2       = (const float*)d_in[16];
    const float* head_b2       = (const float*)d_in[17];
    const int*   edge_index    = (const int*)d_in[18];
    const int* src0 = edge_index;
    const int* dst0 = edge_index + N_EDGES;
    float* out = (float*)d_out;

    char* cur = (char*)d_ws;
    auto alloc = [&](size_t bytes) { char* p = cur; cur += (bytes + 255) & ~(size_t)255; return p; };
    unsigned short* x_bf   = (unsigned short*)alloc((size_t)N_NODES * HDIM * 2);
    unsigned short* agg    = (unsigned short*)alloc((size_t)N_NODES * NH * 2);
    unsigned short* y_bf   = (unsigned short*)alloc((size_t)N_NODES * HDIM * 2);
    unsigned short* nf_bf  = (unsigned short*)alloc((size_t)N_NODES * NDIM * 2);
    unsigned short* enc_wt = (unsigned short*)alloc((size_t)HDIM * NDIM * 2);
    unsigned short* gw2t   = (unsigned short*)alloc((size_t)NLAYERS * NH * HDIM * 2);
    unsigned short* hw1t   = (unsigned short*)alloc((size_t)512 * HDIM * 2);
    float* ws_s   = (float*)alloc((size_t)NLAYERS * 4 * HDIM * 4);
    float* ws_d   = (float*)alloc((size_t)NLAYERS * 4 * HDIM * 4);
    float* a_s    = (float*)alloc((size_t)N_NODES * 4 * 4);
    float* a_d    = (float*)alloc((size_t)N_NODES * 4 * 4);
    float* ewCSR4 = (float*)alloc((size_t)N_EDGES * 4 * 4);
    float* wmean3 = (float*)alloc(192 * 4);
    float* scal3  = (float*)alloc(24 * 4);
    // cnt+fillc contiguous: single memset must cover both exactly
    int* cnt      = (int*)alloc((size_t)2 * N_NODES * 4);
    int* fillc    = cnt + N_NODES;
    int* row_ptr  = (int*)alloc((size_t)(N_NODES + 1) * 4);
    int* srcCSR   = (int*)alloc((size_t)N_EDGES * 4);

    hipMemsetAsync(cnt, 0, (size_t)2 * N_NODES * sizeof(int), stream);

    prep_combo<<<PC_TOTAL, 256, 0, stream>>>(
        node_features, nf_bf, enc_w, enc_wt, gat_w, gw2t, att_src, att_dst,
        ws_s, ws_d, head_w1, hw1t, edge_enc_w, edge_enc_b, lin_edge_w, att_edge,
        wmean3, scal3, dst0, cnt, a_s, a_d);
    scan_full<<<1, 1024, 0, stream>>>(cnt, row_ptr);
    fill_ew<<<(N_EDGES + 255) / 256, 256, 0, stream>>>(src0, dst0, edge_attr, wmean3, scal3,
                                                       row_ptr, fillc, srcCSR, ewCSR4);

    const int GEMM_GRID_256 = 8 * (((N_NODES + 63) / 64 + 7) / 8) * (256 / 128);  // 640
    const int GRID_HEAD = 8 * (((N_NODES + 63) / 64 + 7) / 8) * (512 / 128);      // 1280

    // encoder GEMM with fused layer-0 attn-dot partials (atomicAdd into zeroed a_s/a_d)
    gemm_bf16<true, true, true><<<GEMM_GRID_256, 256, 0, stream>>>(
        nf_bf, enc_wt, enc_b, x_bf, N_NODES, HDIM, NDIM, ws_s, ws_d, a_s, a_d);

    for (int l = 0; l < NLAYERS; l++) {
        gat_agg_fused<<<N_NODES / 8, 256, 0, stream>>>(
            x_bf, a_s, a_d, scal3 + l * 8, row_ptr, srcCSR, ewCSR4, l, agg);
        gemm_bf16<false, true, false><<<GEMM_GRID_256, 256, 0, stream>>>(
            agg, gw2t + (size_t)l * NH * HDIM, gat_b + (size_t)l * HDIM, y_bf,
            N_NODES, HDIM, NH);
        if (l < NLAYERS - 1) {
            ln_residual<true, false><<<N_NODES / 4, 256, 0, stream>>>(
                y_bf, ln_g + (size_t)l * HDIM, ln_b + (size_t)l * HDIM, x_bf,
                ws_s + (size_t)(l + 1) * 4 * HDIM, ws_d + (size_t)(l + 1) * 4 * HDIM,
                a_s, a_d, nullptr);
        } else {
            ln_residual<false, true><<<N_NODES / 4, 256, 0, stream>>>(
                y_bf, ln_g + (size_t)l * HDIM, ln_b + (size_t)l * HDIM, x_bf,
                nullptr, nullptr, nullptr, nullptr, out + 4 * N_NODES);
        }
    }

    gemm_head<<<GRID_HEAD, 256, 0, stream>>>(
        x_bf, hw1t, head_b1, N_NODES, 512, HDIM, head_w2, head_b2, out);
}

// Round 9
// 405.391 us; speedup vs baseline: 1.0231x; 1.0231x over previous
//
#include <hip/hip_runtime.h>
#include <math.h>

#define N_NODES 20000
#define N_EDGES 200000
#define NDIM 128
#define EDIM 64
#define HDIM 256
#define HEADS 4
#define NH 1024
#define NLAYERS 3

typedef __attribute__((ext_vector_type(8))) short short8;
typedef __attribute__((ext_vector_type(4))) float floatx4;

__device__ __forceinline__ float b2f(unsigned short u) {
    union { unsigned u; float f; } c; c.u = ((unsigned)u) << 16; return c.f;
}
__device__ __forceinline__ float b2f_lo(unsigned u) {
    union { unsigned u; float f; } c; c.u = u << 16; return c.f;
}
__device__ __forceinline__ float b2f_hi(unsigned u) {
    union { unsigned u; float f; } c; c.u = u & 0xffff0000u; return c.f;
}
__device__ __forceinline__ unsigned short f2b(float f) {
    union { float f; unsigned u; } c; c.f = f;
    unsigned u = c.u;
    return (unsigned short)((u + 0x7FFFu + ((u >> 16) & 1u)) >> 16);
}
__device__ __forceinline__ float lrelu(float v) { return v > 0.f ? v : 0.2f * v; }

// ---------------- CSR scan ----------------
// single-block scan of 20000 counts -> exclusive row_ptr (+ total at [N])
__global__ __launch_bounds__(1024) void scan_full(const int* __restrict__ cnt,
                                                  int* __restrict__ row_ptr) {
    const int PER = 20;   // 1024*20 = 20480 >= 20000
    __shared__ int wtot[16];
    int t = threadIdx.x, lane = t & 63, wid = t >> 6;
    int base = t * PER;
    int loc[PER];
    int s = 0;
    #pragma unroll
    for (int i = 0; i < PER; i++) {
        int idx = base + i;
        int v = (idx < N_NODES) ? cnt[idx] : 0;
        loc[i] = s; s += v;
    }
    int inc = s;
    #pragma unroll
    for (int off = 1; off < 64; off <<= 1) {
        int tt = __shfl_up(inc, off, 64);
        if (lane >= off) inc += tt;
    }
    if (lane == 63) wtot[wid] = inc;
    __syncthreads();
    int woff = 0;
    #pragma unroll
    for (int w = 0; w < 16; w++) if (w < wid) woff += wtot[w];
    int excl = woff + inc - s;
    #pragma unroll
    for (int i = 0; i < PER; i++) {
        int idx = base + i;
        if (idx < N_NODES) row_ptr[idx] = excl + loc[i];
    }
    if (t == 1023) row_ptr[N_NODES] = excl + s;
}

// fill CSR + fused edge-weight MLP (3 layers' scalar weights) -> ewCSR4[pos]
__global__ __launch_bounds__(256) void fill_ew(const int* __restrict__ src0,
                                               const int* __restrict__ dst0,
                                               const float* __restrict__ edge_attr,
                                               const float* __restrict__ wmean3,
                                               const float* __restrict__ scal3,
                                               const int* __restrict__ row_ptr,
                                               int* __restrict__ fillc,
                                               int* __restrict__ srcCSR,
                                               float* __restrict__ ewCSR4) {
    int e = blockIdx.x * 256 + threadIdx.x;
    if (e >= N_EDGES) return;
    int d = dst0[e];
    int p = atomicAdd(&fillc[d], 1);
    int pos = row_ptr[d] + p;
    srcCSR[pos] = src0[e];
    const float* row = edge_attr + (size_t)e * EDIM;
    float s0 = 0.f, s1 = 0.f, s2 = 0.f;
    #pragma unroll
    for (int dd = 0; dd < EDIM; dd += 4) {
        float4 a  = *(const float4*)(row + dd);
        float4 w0 = *(const float4*)(wmean3 + dd);
        float4 w1 = *(const float4*)(wmean3 + 64 + dd);
        float4 w2 = *(const float4*)(wmean3 + 128 + dd);
        s0 += a.x * w0.x + a.y * w0.y + a.z * w0.z + a.w * w0.w;
        s1 += a.x * w1.x + a.y * w1.y + a.z * w1.z + a.w * w1.w;
        s2 += a.x * w2.x + a.y * w2.y + a.z * w2.z + a.w * w2.w;
    }
    *(float4*)(ewCSR4 + (size_t)pos * 4) =
        make_float4(s0 + scal3[4], s1 + scal3[12], s2 + scal3[20], 0.f);
}

// ---------------- combined prep über-kernel (all 256-thread blocks) -------------
// ranges: conv | transpose enc | gat_w_prep | ws_prep | transpose hw1 | layer_prep3
//         | edge histogram (folded hist_kernel: independent work, -1 dispatch)
#define PC_CONV   2500
#define PC_TENC   (PC_CONV + 32)
#define PC_GWP    (PC_TENC + 768)
#define PC_WSP    (PC_GWP + 12)
#define PC_THW1   (PC_WSP + 128)
#define PC_LP3    (PC_THW1 + 3)
#define PC_HIST   (PC_LP3 + 782)     // 782*256 >= 200000
#define PC_TOTAL  PC_HIST

__device__ void transpose_body(const float* in, unsigned short* out, int K, int Nn,
                               int bx, int by, float sh[32][33], float scale) {
    int tid = threadIdx.x;
    int tx = tid & 31, ty = tid >> 5;
    int kb = by * 32, nb = bx * 32;
    #pragma unroll
    for (int i = 0; i < 32; i += 8)
        sh[ty + i][tx] = in[(size_t)(kb + ty + i) * Nn + nb + tx];
    __syncthreads();
    #pragma unroll
    for (int i = 0; i < 32; i += 8)
        out[(size_t)(nb + ty + i) * K + kb + tx] = f2b(scale * sh[tx][ty + i]);
}

__global__ __launch_bounds__(256) void prep_combo(
    const float* __restrict__ node_features, unsigned short* __restrict__ nf_bf,
    const float* __restrict__ enc_w, unsigned short* __restrict__ enc_wt,
    const float* __restrict__ gat_w, unsigned short* __restrict__ gw2t,
    const float* __restrict__ att_src, const float* __restrict__ att_dst,
    float* __restrict__ ws_s, float* __restrict__ ws_d,
    const float* __restrict__ head_w1, unsigned short* __restrict__ hw1t,
    const float* __restrict__ edge_enc_w, const float* __restrict__ edge_enc_b,
    const float* __restrict__ lin_edge_w, const float* __restrict__ att_edge,
    float* __restrict__ wmean3, float* __restrict__ scal3,
    const int* __restrict__ dst0, int* __restrict__ cnt)
{
    __shared__ float sh[32][33];
    int b = blockIdx.x;
    int tid = threadIdx.x;
    if (b < PC_CONV) {
        int i = b * 256 + tid;
        float4 v = ((const float4*)node_features)[i];
        ushort4 o;
        o.x = f2b(v.x); o.y = f2b(v.y); o.z = f2b(v.z); o.w = f2b(v.w);
        ((ushort4*)nf_bf)[i] = o;
    } else if (b < PC_TENC) {
        int b2 = b - PC_CONV;
        transpose_body(enc_w, enc_wt, NDIM, HDIM, b2 & 7, b2 >> 3, sh, 1.f);
    } else if (b < PC_GWP) {
        int b3 = b - PC_TENC;
        int bx = b3 & 7, by = (b3 >> 3) & 7, z = b3 >> 6;
        int l = z >> 2, h = z & 3;
        const float* src = gat_w + (size_t)l * HDIM * NH + (size_t)h * HDIM;
        unsigned short* dst = gw2t + (size_t)l * HDIM * NH + (size_t)h * HDIM;
        int tx = tid & 31, ty = tid >> 5;
        int kb = by * 32, db = bx * 32;
        #pragma unroll
        for (int i = 0; i < 32; i += 8)
            sh[ty + i][tx] = src[(size_t)(kb + ty + i) * NH + db + tx];
        __syncthreads();
        #pragma unroll
        for (int i = 0; i < 32; i += 8)
            dst[(size_t)(db + ty + i) * NH + kb + tx] = f2b(0.25f * sh[tx][ty + i]);
    } else if (b < PC_WSP) {
        int bx = b - PC_GWP;
        int l = bx >> 2, h = bx & 3;
        int k = tid;
        const float* wrow = gat_w + (size_t)l * HDIM * NH + (size_t)k * NH + h * HDIM;
        const float* as = att_src + (size_t)l * NH + h * HDIM;
        const float* ad = att_dst + (size_t)l * NH + h * HDIM;
        float s1 = 0.f, s2 = 0.f;
        for (int d = 0; d < HDIM; d += 4) {
            float4 w4 = *(const float4*)(wrow + d);
            float4 a4 = *(const float4*)(as + d);
            float4 b4 = *(const float4*)(ad + d);
            s1 += w4.x * a4.x + w4.y * a4.y + w4.z * a4.z + w4.w * a4.w;
            s2 += w4.x * b4.x + w4.y * b4.y + w4.z * b4.z + w4.w * b4.w;
        }
        ws_s[(size_t)bx * HDIM + k] = s1;
        ws_d[(size_t)bx * HDIM + k] = s2;
    } else if (b < PC_THW1) {
        int b4 = b - PC_WSP;
        int bx = b4 & 3, by = (b4 >> 2) & 7, z = b4 >> 5;
        transpose_body(head_w1 + (size_t)z * HDIM * 128,
                       hw1t + (size_t)z * 128 * HDIM, HDIM, 128, bx, by, sh, 1.f);
    } else if (b < PC_LP3) {
        int l = b - PC_THW1;
        const float* eew = edge_enc_w + (size_t)l * EDIM * HDIM;
        const float* eeb = edge_enc_b + (size_t)l * HDIM;
        const float* lew = lin_edge_w + (size_t)l * NH;
        const float* ae  = att_edge + (size_t)l * NH;
        float* wm = wmean3 + l * 64;
        float* sc = scal3 + l * 8;
        if (tid < 64) {
            float s = 0.f;
            for (int d = 0; d < HDIM; d++) s += eew[tid * HDIM + d];
            wm[tid] = s * (1.f / HDIM);
        } else if (tid < 68) {
            int h = tid - 64;
            float s = 0.f;
            for (int d = 0; d < HDIM; d++) s += lew[h * HDIM + d] * ae[h * HDIM + d];
            sc[h] = s;
        } else if (tid == 68) {
            float s = 0.f;
            for (int d = 0; d < HDIM; d++) s += eeb[d];
            sc[4] = s * (1.f / HDIM);
        }
    } else {
        int e = (b - PC_LP3) * 256 + tid;
        if (e < N_EDGES) atomicAdd(&cnt[dst0[e]], 1);
    }
}

// ---------------- bf16 MFMA GEMM: BM=64, BN=128, BK=64, XCD-grouped grid --------
template <bool RELU, bool BIAS>
__global__ __launch_bounds__(256) void gemm_bf16(
    const unsigned short* __restrict__ A, const unsigned short* __restrict__ Bt,
    const float* __restrict__ bias, unsigned short* __restrict__ C,
    int M, int Ntot, int K)
{
    __shared__ char lds[24576];
    unsigned short* As = (unsigned short*)lds;            // 2 planes of 64x32 (8 KB)
    unsigned short* Bs = (unsigned short*)(lds + 8192);   // 2 planes of 128x32 (16 KB)
    unsigned short* Cs = (unsigned short*)lds;            // 64 x 128 bf16 epilogue

    int Cb = Ntot >> 7;
    int P  = (M + 63) >> 6;
    int d  = blockIdx.x;
    int xcd = d & 7;
    int i5  = d >> 3;
    int p   = xcd + 8 * (i5 / Cb);
    int cblk = i5 % Cb;
    if (p >= P) return;
    int row0 = p * 64;
    int col0 = cblk * 128;

    int tid = threadIdx.x;
    int lane = tid & 63;
    int wid = tid >> 6;
    int wm = (wid >> 1) * 32;
    int wn = (wid & 1) * 64;
    int lm = lane & 15;
    int q8 = (lane >> 4) * 8;
    int q4 = (lane >> 4) * 4;

    floatx4 acc[2][4];
    #pragma unroll
    for (int i = 0; i < 2; i++)
        #pragma unroll
        for (int j = 0; j < 4; j++)
            acc[i][j] = (floatx4)(0.f);

    int arow = tid >> 2;
    int acol = (tid & 3) * 8;
    int garow = row0 + arow; if (garow > M - 1) garow = M - 1;

    for (int k0 = 0; k0 < K; k0 += 64) {
        #pragma unroll
        for (int kk = 0; kk < 2; kk++) {
            int kb = k0 + kk * 32;
            __builtin_amdgcn_global_load_lds(
                (__attribute__((address_space(1))) const void*)(A + (size_t)garow * K + kb + acol),
                (__attribute__((address_space(3))) void*)(As + kk * 2048 + tid * 8), 16, 0, 0);
            #pragma unroll
            for (int r = 0; r < 2; r++) {
                int chunk = tid + r * 256;
                int brow = chunk >> 2;
                int bcol = (chunk & 3) * 8;
                __builtin_amdgcn_global_load_lds(
                    (__attribute__((address_space(1))) const void*)(Bt + (size_t)(col0 + brow) * K + kb + bcol),
                    (__attribute__((address_space(3))) void*)(Bs + kk * 4096 + chunk * 8), 16, 0, 0);
            }
        }
        __syncthreads();
        #pragma unroll
        for (int kk = 0; kk < 2; kk++) {
            short8 af[2], bf[4];
            #pragma unroll
            for (int i = 0; i < 2; i++)
                af[i] = *(const short8*)(As + kk * 2048 + (wm + i * 16 + lm) * 32 + q8);
            #pragma unroll
            for (int j = 0; j < 4; j++)
                bf[j] = *(const short8*)(Bs + kk * 4096 + (wn + j * 16 + lm) * 32 + q8);
            #pragma unroll
            for (int i = 0; i < 2; i++)
                #pragma unroll
                for (int j = 0; j < 4; j++)
                    acc[i][j] = __builtin_amdgcn_mfma_f32_16x16x32_bf16(af[i], bf[j], acc[i][j], 0, 0, 0);
        }
        __syncthreads();
    }

    #pragma unroll
    for (int i = 0; i < 2; i++) {
        #pragma unroll
        for (int j = 0; j < 4; j++) {
            int cl = wn + j * 16 + lm;
            float bv = BIAS ? bias[col0 + cl] : 0.f;
            #pragma unroll
            for (int reg = 0; reg < 4; reg++) {
                int rl = wm + i * 16 + q4 + reg;
                float v = acc[i][j][reg];
                if (BIAS) v += bv;
                if (RELU) v = fmaxf(v, 0.f);
                Cs[rl * 128 + cl] = f2b(v);
            }
        }
    }
    __syncthreads();
    int row = tid >> 2;
    int seg = (tid & 3) * 32;
    if (row0 + row < M) {
        #pragma unroll
        for (int u = 0; u < 4; u++) {
            int4 v = *(const int4*)(Cs + row * 128 + seg + u * 8);
            *(int4*)(C + (size_t)(row0 + row) * Ntot + col0 + seg + u * 8) = v;
        }
    }
}

// ---------------- head GEMM (BM=64, BN=128, BK=64) + fused per-head [128->1] ----
__global__ __launch_bounds__(256) void gemm_head(
    const unsigned short* __restrict__ A, const unsigned short* __restrict__ Bt,
    const float* __restrict__ bias, int M, int Ntot, int K,
    const float* __restrict__ w2, const float* __restrict__ b2v,
    float* __restrict__ outp)
{
    __shared__ char lds[24576];
    unsigned short* As = (unsigned short*)lds;
    unsigned short* Bs = (unsigned short*)(lds + 8192);
    unsigned short* Cs = (unsigned short*)lds;

    int Cb = Ntot >> 7;
    int P  = (M + 63) >> 6;
    int d  = blockIdx.x;
    int xcd = d & 7;
    int i5  = d >> 3;
    int p   = xcd + 8 * (i5 / Cb);
    int cblk = i5 % Cb;
    if (p >= P) return;
    int row0 = p * 64;
    int col0 = cblk * 128;

    int tid = threadIdx.x;
    int lane = tid & 63;
    int wid = tid >> 6;
    int wm = (wid >> 1) * 32;
    int wn = (wid & 1) * 64;
    int lm = lane & 15;
    int q8 = (lane >> 4) * 8;
    int q4 = (lane >> 4) * 4;

    floatx4 acc[2][4];
    #pragma unroll
    for (int i = 0; i < 2; i++)
        #pragma unroll
        for (int j = 0; j < 4; j++)
            acc[i][j] = (floatx4)(0.f);

    int arow = tid >> 2;
    int acol = (tid & 3) * 8;
    int garow = row0 + arow; if (garow > M - 1) garow = M - 1;

    for (int k0 = 0; k0 < K; k0 += 64) {
        #pragma unroll
        for (int kk = 0; kk < 2; kk++) {
            int kb = k0 + kk * 32;
            __builtin_amdgcn_global_load_lds(
                (__attribute__((address_space(1))) const void*)(A + (size_t)garow * K + kb + acol),
                (__attribute__((address_space(3))) void*)(As + kk * 2048 + tid * 8), 16, 0, 0);
            #pragma unroll
            for (int r = 0; r < 2; r++) {
                int chunk = tid + r * 256;
                int brow = chunk >> 2;
                int bcol = (chunk & 3) * 8;
                __builtin_amdgcn_global_load_lds(
                    (__attribute__((address_space(1))) const void*)(Bt + (size_t)(col0 + brow) * K + kb + bcol),
                    (__attribute__((address_space(3))) void*)(Bs + kk * 4096 + chunk * 8), 16, 0, 0);
            }
        }
        __syncthreads();
        #pragma unroll
        for (int kk = 0; kk < 2; kk++) {
            short8 af[2], bf[4];
            #pragma unroll
            for (int i = 0; i < 2; i++)
                af[i] = *(const short8*)(As + kk * 2048 + (wm + i * 16 + lm) * 32 + q8);
            #pragma unroll
            for (int j = 0; j < 4; j++)
                bf[j] = *(const short8*)(Bs + kk * 4096 + (wn + j * 16 + lm) * 32 + q8);
            #pragma unroll
            for (int i = 0; i < 2; i++)
                #pragma unroll
                for (int j = 0; j < 4; j++)
                    acc[i][j] = __builtin_amdgcn_mfma_f32_16x16x32_bf16(af[i], bf[j], acc[i][j], 0, 0, 0);
        }
        __syncthreads();
    }

    #pragma unroll
    for (int i = 0; i < 2; i++) {
        #pragma unroll
        for (int j = 0; j < 4; j++) {
            int cl = wn + j * 16 + lm;
            float bv = bias[col0 + cl];
            #pragma unroll
            for (int reg = 0; reg < 4; reg++) {
                int rl = wm + i * 16 + q4 + reg;
                float v = fmaxf(acc[i][j][reg] + bv, 0.f);
                Cs[rl * 128 + cl] = f2b(v);
            }
        }
    }
    __syncthreads();
    int row = tid >> 2;
    int seg = (tid & 3) * 32;
    int k = col0 >> 7;
    const float* wr = w2 + k * 128;
    const unsigned short* cr = Cs + row * 128 + seg;
    float s = 0.f;
    #pragma unroll
    for (int u = 0; u < 4; u++) {
        int4 v = *(const int4*)(cr + u * 8);
        float4 w0 = *(const float4*)(wr + seg + u * 8);
        float4 w1 = *(const float4*)(wr + seg + u * 8 + 4);
        s += b2f_lo((unsigned)v.x) * w0.x + b2f_hi((unsigned)v.x) * w0.y
           + b2f_lo((unsigned)v.y) * w0.z + b2f_hi((unsigned)v.y) * w0.w;
        s += b2f_lo((unsigned)v.z) * w1.x + b2f_hi((unsigned)v.z) * w1.y
           + b2f_lo((unsigned)v.w) * w1.z + b2f_hi((unsigned)v.w) * w1.w;
    }
    s += __shfl_xor(s, 1, 64);
    s += __shfl_xor(s, 2, 64);
    if ((tid & 3) == 0 && row0 + row < M) {
        s += b2v[k];
        if (k == 0 || k == 3) s = 1.f / (1.f + __expf(-s));
        outp[(size_t)k * N_NODES + row0 + row] = s;
    }
}

// a_s/a_d from x: wave per node, 4 nodes/block (layer 0 only; fused afterwards)
__global__ __launch_bounds__(256) void attn_x(const unsigned short* __restrict__ x_bf,
                                              const float* __restrict__ ws_s,
                                              const float* __restrict__ ws_d,
                                              float* __restrict__ a_s,
                                              float* __restrict__ a_d)
{
    int wid = threadIdx.x >> 6, lane = threadIdx.x & 63;
    int n = blockIdx.x * 4 + wid;
    ushort4 xv = *(const ushort4*)(x_bf + (size_t)n * HDIM + lane * 4);
    float x0 = b2f(xv.x), x1 = b2f(xv.y), x2 = b2f(xv.z), x3 = b2f(xv.w);
    float ss[4], sd[4];
    #pragma unroll
    for (int h = 0; h < 4; h++) {
        float4 s4 = *(const float4*)(ws_s + h * HDIM + lane * 4);
        float4 d4 = *(const float4*)(ws_d + h * HDIM + lane * 4);
        ss[h] = x0 * s4.x + x1 * s4.y + x2 * s4.z + x3 * s4.w;
        sd[h] = x0 * d4.x + x1 * d4.y + x2 * d4.z + x3 * d4.w;
    }
    #pragma unroll
    for (int off = 32; off > 0; off >>= 1)
        #pragma unroll
        for (int h = 0; h < 4; h++) {
            ss[h] += __shfl_xor(ss[h], off, 64);
            sd[h] += __shfl_xor(sd[h], off, 64);
        }
    if (lane == 0) {
        *(float4*)(a_s + n * 4) = make_float4(ss[0], ss[1], ss[2], ss[3]);
        *(float4*)(a_d + n * 4) = make_float4(sd[0], sd[1], sd[2], sd[3]);
    }
}

// Fused edge-logits + softmax + aggregate + in-wave self-loop weight.
// TWO nodes per wave (half-wave of 32 lanes, 16 B/lane gathers -> each
// global_load_dwordx4 fetches 1 KB = two x-rows). 8 nodes/block.
// ALL accumulators are named floatx4 registers - no arrays, no spill.
__global__ __launch_bounds__(256) void gat_agg_fused(
    const unsigned short* __restrict__ x_bf, const float* __restrict__ a_s,
    const float* __restrict__ a_d,
    const float* __restrict__ scal, const int* __restrict__ row_ptr,
    const int* __restrict__ srcCSR, const float* __restrict__ ewCSR4,
    int l, unsigned short* __restrict__ agg)
{
    int sub = threadIdx.x & 31;
    int hw  = threadIdx.x >> 5;               // half-wave id 0..7
    int n = blockIdx.x * 8 + hw;
    int r0 = row_ptr[n];
    int deg = row_ptr[n + 1] - r0;
    int cnt = deg + 1;
    int cntMax = max(cnt, __shfl_xor(cnt, 32, 64));   // wave-uniform bound

    float4 c4 = *(const float4*)scal;
    float4 as4 = *(const float4*)(a_s + (size_t)n * 4);
    float4 ad4 = *(const float4*)(a_d + (size_t)n * 4);

    // chunk-0 edge data in registers; row-sum of w for the self-loop weight
    int sv0 = n; float w0 = 0.f;
    if (sub < deg) {
        sv0 = srcCSR[r0 + sub];
        w0 = ewCSR4[(((size_t)(r0 + sub)) << 2) + l];
    }
    float sw = w0;
    for (int i = 32 + sub; i < deg; i += 32)
        sw += ewCSR4[(((size_t)(r0 + i)) << 2) + l];
    #pragma unroll
    for (int off = 16; off > 0; off >>= 1) sw += __shfl_xor(sw, off, 32);
    float lw = sw / fmaxf((float)deg, 1.f);

    float4 zself;
    zself.x = lrelu(as4.x + ad4.x + c4.x * lw);
    zself.y = lrelu(as4.y + ad4.y + c4.y * lw);
    zself.z = lrelu(as4.z + ad4.z + c4.z * lw);
    zself.w = lrelu(as4.w + ad4.w + c4.w * lw);

    auto comp_z = [&](int c0, int& sv, float4& z) {
        int ix = c0 + sub;
        if (ix < deg) {
            sv = srcCSR[r0 + ix];
            float w = ewCSR4[(((size_t)(r0 + ix)) << 2) + l];
            float4 zs = *(const float4*)(a_s + (size_t)sv * 4);
            z.x = lrelu(zs.x + ad4.x + c4.x * w);
            z.y = lrelu(zs.y + ad4.y + c4.y * w);
            z.z = lrelu(zs.z + ad4.z + c4.z * w);
            z.w = lrelu(zs.w + ad4.w + c4.w * w);
        } else if (ix == deg) {
            sv = n; z = zself;
        } else {
            sv = n; z.x = z.y = z.z = z.w = -1e30f;
        }
    };

    float4 z0;
    if (sub < deg) {
        float4 zs = *(const float4*)(a_s + (size_t)sv0 * 4);
        z0.x = lrelu(zs.x + ad4.x + c4.x * w0);
        z0.y = lrelu(zs.y + ad4.y + c4.y * w0);
        z0.z = lrelu(zs.z + ad4.z + c4.z * w0);
        z0.w = lrelu(zs.w + ad4.w + c4.w * w0);
    } else if (sub == deg) {
        z0 = zself;
    } else {
        z0.x = z0.y = z0.z = z0.w = -1e30f;
    }

    // no max-subtraction: logits O(1-3) here (softmax shift-invariant, f32-exact)
    float4 p0;
    p0.x = __expf(z0.x); p0.y = __expf(z0.y);
    p0.z = __expf(z0.z); p0.w = __expf(z0.w);
    float s0 = p0.x, s1 = p0.y, s2 = p0.z, s3 = p0.w;
    for (int c0 = 32; c0 < cnt; c0 += 32) {     // no shfl inside: per-half bound ok
        int sv; float4 z; comp_z(c0, sv, z);
        s0 += __expf(z.x); s1 += __expf(z.y);
        s2 += __expf(z.z); s3 += __expf(z.w);
    }
    #pragma unroll
    for (int off = 16; off > 0; off >>= 1) {
        s0 += __shfl_xor(s0, off, 32);
        s1 += __shfl_xor(s1, off, 32);
        s2 += __shfl_xor(s2, off, 32);
        s3 += __shfl_xor(s3, off, 32);
    }
    float i0 = 1.f / s0, i1 = 1.f / s1, i2 = 1.f / s2, i3 = 1.f / s3;
    float4 al0;
    al0.x = p0.x * i0; al0.y = p0.y * i1; al0.z = p0.z * i2; al0.w = p0.w * i3;

    // 8 named vector accumulators (4 heads x {lo,hi} halves of this lane's 8 dims)
    floatx4 acc0l = (floatx4)(0.f), acc0h = (floatx4)(0.f);
    floatx4 acc1l = (floatx4)(0.f), acc1h = (floatx4)(0.f);
    floatx4 acc2l = (floatx4)(0.f), acc2h = (floatx4)(0.f);
    floatx4 acc3l = (floatx4)(0.f), acc3h = (floatx4)(0.f);
    const unsigned short* xw = x_bf + (size_t)sub * 8;

    auto acc_one = [&](uint4 u, float a0, float a1, float a2, float a3) {
        floatx4 xl, xh;
        xl[0] = b2f_lo(u.x); xl[1] = b2f_hi(u.x);
        xl[2] = b2f_lo(u.y); xl[3] = b2f_hi(u.y);
        xh[0] = b2f_lo(u.z); xh[1] = b2f_hi(u.z);
        xh[2] = b2f_lo(u.w); xh[3] = b2f_hi(u.w);
        acc0l += xl * a0; acc0h += xh * a0;
        acc1l += xl * a1; acc1h += xh * a1;
        acc2l += xl * a2; acc2h += xh * a2;
        acc3l += xl * a3; acc3h += xh * a3;
    };

    auto agg_chunk = [&](int sv, float4 al, int mc) {   // mc is wave-uniform
        int j = 0;
        for (; j + 3 < mc; j += 4) {
            int sA = __shfl(sv, j, 32);
            int sB = __shfl(sv, j + 1, 32);
            int sC = __shfl(sv, j + 2, 32);
            int sD = __shfl(sv, j + 3, 32);
            uint4 uA = *(const uint4*)(xw + (size_t)sA * HDIM);
            uint4 uB = *(const uint4*)(xw + (size_t)sB * HDIM);
            uint4 uC = *(const uint4*)(xw + (size_t)sC * HDIM);
            uint4 uD = *(const uint4*)(xw + (size_t)sD * HDIM);
            acc_one(uA, __shfl(al.x, j, 32), __shfl(al.y, j, 32),
                        __shfl(al.z, j, 32), __shfl(al.w, j, 32));
            acc_one(uB, __shfl(al.x, j + 1, 32), __shfl(al.y, j + 1, 32),
                        __shfl(al.z, j + 1, 32), __shfl(al.w, j + 1, 32));
            acc_one(uC, __shfl(al.x, j + 2, 32), __shfl(al.y, j + 2, 32),
                        __shfl(al.z, j + 2, 32), __shfl(al.w, j + 2, 32));
            acc_one(uD, __shfl(al.x, j + 3, 32), __shfl(al.y, j + 3, 32),
                        __shfl(al.z, j + 3, 32), __shfl(al.w, j + 3, 32));
        }
        for (; j + 1 < mc; j += 2) {
            int sA = __shfl(sv, j, 32);
            int sB = __shfl(sv, j + 1, 32);
            uint4 uA = *(const uint4*)(xw + (size_t)sA * HDIM);
            uint4 uB = *(const uint4*)(xw + (size_t)sB * HDIM);
            acc_one(uA, __shfl(al.x, j, 32), __shfl(al.y, j, 32),
                        __shfl(al.z, j, 32), __shfl(al.w, j, 32));
            acc_one(uB, __shfl(al.x, j + 1, 32), __shfl(al.y, j + 1, 32),
                        __shfl(al.z, j + 1, 32), __shfl(al.w, j + 1, 32));
        }
        if (j < mc) {
            int sA = __shfl(sv, j, 32);
            uint4 uA = *(const uint4*)(xw + (size_t)sA * HDIM);
            acc_one(uA, __shfl(al.x, j, 32), __shfl(al.y, j, 32),
                        __shfl(al.z, j, 32), __shfl(al.w, j, 32));
        }
    };

    agg_chunk(sv0, al0, min(32, cntMax));
    for (int c0 = 32; c0 < cntMax; c0 += 32) {          // uniform bound (shfl inside)
        int sv; float4 z; comp_z(c0, sv, z);
        float4 al;
        al.x = __expf(z.x) * i0; al.y = __expf(z.y) * i1;
        al.z = __expf(z.z) * i2; al.w = __expf(z.w) * i3;
        agg_chunk(sv, al, min(32, cntMax - c0));
    }

    unsigned short* ag = agg + (size_t)n * NH + sub * 8;
    {
        uint4 o;
        o.x = (unsigned)f2b(acc0l[0]) | ((unsigned)f2b(acc0l[1]) << 16);
        o.y = (unsigned)f2b(acc0l[2]) | ((unsigned)f2b(acc0l[3]) << 16);
        o.z = (unsigned)f2b(acc0h[0]) | ((unsigned)f2b(acc0h[1]) << 16);
        o.w = (unsigned)f2b(acc0h[2]) | ((unsigned)f2b(acc0h[3]) << 16);
        *(uint4*)(ag + 0 * 256) = o;
    }
    {
        uint4 o;
        o.x = (unsigned)f2b(acc1l[0]) | ((unsigned)f2b(acc1l[1]) << 16);
        o.y = (unsigned)f2b(acc1l[2]) | ((unsigned)f2b(acc1l[3]) << 16);
        o.z = (unsigned)f2b(acc1h[0]) | ((unsigned)f2b(acc1h[1]) << 16);
        o.w = (unsigned)f2b(acc1h[2]) | ((unsigned)f2b(acc1h[3]) << 16);
        *(uint4*)(ag + 1 * 256) = o;
    }
    {
        uint4 o;
        o.x = (unsigned)f2b(acc2l[0]) | ((unsigned)f2b(acc2l[1]) << 16);
        o.y = (unsigned)f2b(acc2l[2]) | ((unsigned)f2b(acc2l[3]) << 16);
        o.z = (unsigned)f2b(acc2h[0]) | ((unsigned)f2b(acc2h[1]) << 16);
        o.w = (unsigned)f2b(acc2h[2]) | ((unsigned)f2b(acc2h[3]) << 16);
        *(uint4*)(ag + 2 * 256) = o;
    }
    {
        uint4 o;
        o.x = (unsigned)f2b(acc3l[0]) | ((unsigned)f2b(acc3l[1]) << 16);
        o.y = (unsigned)f2b(acc3l[2]) | ((unsigned)f2b(acc3l[3]) << 16);
        o.z = (unsigned)f2b(acc3h[0]) | ((unsigned)f2b(acc3h[1]) << 16);
        o.w = (unsigned)f2b(acc3h[2]) | ((unsigned)f2b(acc3h[3]) << 16);
        *(uint4*)(ag + 3 * 256) = o;
    }
}

// LN(y) + residual ReLU, in-place x. One wave per node.
template <bool ATTN, bool EMB>
__global__ __launch_bounds__(256) void ln_residual(const unsigned short* __restrict__ y_bf,
                                                   const float* __restrict__ ln_g,
                                                   const float* __restrict__ ln_b,
                                                   unsigned short* __restrict__ x_bf,
                                                   const float* __restrict__ ws_s,
                                                   const float* __restrict__ ws_d,
                                                   float* __restrict__ a_s,
                                                   float* __restrict__ a_d,
                                                   float* __restrict__ emb_out)
{
    int n = blockIdx.x * 4 + (threadIdx.x >> 6);
    int lane = threadIdx.x & 63;
    ushort4 yv = *(const ushort4*)(y_bf + (size_t)n * HDIM + lane * 4);
    float y0 = b2f(yv.x), y1 = b2f(yv.y), y2 = b2f(yv.z), y3 = b2f(yv.w);
    float s1 = y0 + y1 + y2 + y3;
    float s2 = y0 * y0 + y1 * y1 + y2 * y2 + y3 * y3;
    #pragma unroll
    for (int off = 32; off > 0; off >>= 1) {
        s1 += __shfl_xor(s1, off, 64);
        s2 += __shfl_xor(s2, off, 64);
    }
    float mu = s1 * (1.f / HDIM);
    float var = s2 * (1.f / HDIM) - mu * mu;
    float rsig = rsqrtf(var + 1e-5f);
    float4 g = *(const float4*)(ln_g + lane * 4);
    float4 b = *(const float4*)(ln_b + lane * 4);
    ushort4 xv = *(const ushort4*)(x_bf + (size_t)n * HDIM + lane * 4);
    ushort4 o;
    o.x = f2b(fmaxf(b2f(xv.x) + g.x * (y0 - mu) * rsig + b.x, 0.f));
    o.y = f2b(fmaxf(b2f(xv.y) + g.y * (y1 - mu) * rsig + b.y, 0.f));
    o.z = f2b(fmaxf(b2f(xv.z) + g.z * (y2 - mu) * rsig + b.z, 0.f));
    o.w = f2b(fmaxf(b2f(xv.w) + g.w * (y3 - mu) * rsig + b.w, 0.f));
    *(ushort4*)(x_bf + (size_t)n * HDIM + lane * 4) = o;

    float xn0 = b2f(o.x), xn1 = b2f(o.y), xn2 = b2f(o.z), xn3 = b2f(o.w);
    if (EMB) {
        *(float4*)(emb_out + (size_t)n * HDIM + lane * 4) = make_float4(xn0, xn1, xn2, xn3);
    }
    if (ATTN) {
        float ss[4], sd[4];
        #pragma unroll
        for (int h = 0; h < 4; h++) {
            float4 s4 = *(const float4*)(ws_s + h * HDIM + lane * 4);
            float4 d4 = *(const float4*)(ws_d + h * HDIM + lane * 4);
            ss[h] = xn0 * s4.x + xn1 * s4.y + xn2 * s4.z + xn3 * s4.w;
            sd[h] = xn0 * d4.x + xn1 * d4.y + xn2 * d4.z + xn3 * d4.w;
        }
        #pragma unroll
        for (int off = 32; off > 0; off >>= 1)
            #pragma unroll
            for (int h = 0; h < 4; h++) {
                ss[h] += __shfl_xor(ss[h], off, 64);
                sd[h] += __shfl_xor(sd[h], off, 64);
            }
        if (lane == 0) {
            *(float4*)(a_s + n * 4) = make_float4(ss[0], ss[1], ss[2], ss[3]);
            *(float4*)(a_d + n * 4) = make_float4(sd[0], sd[1], sd[2], sd[3]);
        }
    }
}

extern "C" void kernel_launch(void* const* d_in, const int* in_sizes, int n_in,
                              void* d_out, int out_size, void* d_ws, size_t ws_size,
                              hipStream_t stream) {
    const float* node_features = (const float*)d_in[0];
    const float* edge_attr     = (const float*)d_in[1];
    const float* enc_w         = (const float*)d_in[2];
    const float* enc_b         = (const float*)d_in[3];
    const float* edge_enc_w    = (const float*)d_in[4];
    const float* edge_enc_b    = (const float*)d_in[5];
    const float* gat_w         = (const float*)d_in[6];
    const float* att_src       = (const float*)d_in[7];
    const float* att_dst       = (const float*)d_in[8];
    const float* att_edge      = (const float*)d_in[9];
    const float* lin_edge_w    = (const float*)d_in[10];
    const float* gat_b         = (const float*)d_in[11];
    const float* ln_g          = (const float*)d_in[12];
    const float* ln_b          = (const float*)d_in[13];
    const float* head_w1       = (const float*)d_in[14];
    const float* head_b1       = (const float*)d_in[15];
    const float* head_w2       = (const float*)d_in[16];
    const float* head_b2       = (const float*)d_in[17];
    const int*   edge_index    = (const int*)d_in[18];
    const int* src0 = edge_index;
    const int* dst0 = edge_index + N_EDGES;
    float* out = (float*)d_out;

    char* cur = (char*)d_ws;
    auto alloc = [&](size_t bytes) { char* p = cur; cur += (bytes + 255) & ~(size_t)255; return p; };
    unsigned short* x_bf   = (unsigned short*)alloc((size_t)N_NODES * HDIM * 2);
    unsigned short* agg    = (unsigned short*)alloc((size_t)N_NODES * NH * 2);
    unsigned short* y_bf   = (unsigned short*)alloc((size_t)N_NODES * HDIM * 2);
    unsigned short* nf_bf  = (unsigned short*)alloc((size_t)N_NODES * NDIM * 2);
    unsigned short* enc_wt = (unsigned short*)alloc((size_t)HDIM * NDIM * 2);
    unsigned short* gw2t   = (unsigned short*)alloc((size_t)NLAYERS * NH * HDIM * 2);
    unsigned short* hw1t   = (unsigned short*)alloc((size_t)512 * HDIM * 2);
    float* ws_s   = (float*)alloc((size_t)NLAYERS * 4 * HDIM * 4);
    float* ws_d   = (float*)alloc((size_t)NLAYERS * 4 * HDIM * 4);
    float* a_s    = (float*)alloc((size_t)N_NODES * 4 * 4);
    float* a_d    = (float*)alloc((size_t)N_NODES * 4 * 4);
    float* ewCSR4 = (float*)alloc((size_t)N_EDGES * 4 * 4);
    float* wmean3 = (float*)alloc(192 * 4);
    float* scal3  = (float*)alloc(24 * 4);
    // cnt+fillc contiguous: single memset must cover both exactly
    int* cnt      = (int*)alloc((size_t)2 * N_NODES * 4);
    int* fillc    = cnt + N_NODES;
    int* row_ptr  = (int*)alloc((size_t)(N_NODES + 1) * 4);
    int* srcCSR   = (int*)alloc((size_t)N_EDGES * 4);

    hipMemsetAsync(cnt, 0, (size_t)2 * N_NODES * sizeof(int), stream);

    prep_combo<<<PC_TOTAL, 256, 0, stream>>>(
        node_features, nf_bf, enc_w, enc_wt, gat_w, gw2t, att_src, att_dst,
        ws_s, ws_d, head_w1, hw1t, edge_enc_w, edge_enc_b, lin_edge_w, att_edge,
        wmean3, scal3, dst0, cnt);
    scan_full<<<1, 1024, 0, stream>>>(cnt, row_ptr);
    fill_ew<<<(N_EDGES + 255) / 256, 256, 0, stream>>>(src0, dst0, edge_attr, wmean3, scal3,
                                                       row_ptr, fillc, srcCSR, ewCSR4);

    const int GEMM_GRID_256 = 8 * (((N_NODES + 63) / 64 + 7) / 8) * (256 / 128);  // 640
    const int GRID_HEAD = 8 * (((N_NODES + 63) / 64 + 7) / 8) * (512 / 128);      // 1280

    gemm_bf16<true, true><<<GEMM_GRID_256, 256, 0, stream>>>(
        nf_bf, enc_wt, enc_b, x_bf, N_NODES, HDIM, NDIM);
    attn_x<<<N_NODES / 4, 256, 0, stream>>>(x_bf, ws_s, ws_d, a_s, a_d);

    for (int l = 0; l < NLAYERS; l++) {
        gat_agg_fused<<<N_NODES / 8, 256, 0, stream>>>(
            x_bf, a_s, a_d, scal3 + l * 8, row_ptr, srcCSR, ewCSR4, l, agg);
        gemm_bf16<false, true><<<GEMM_GRID_256, 256, 0, stream>>>(
            agg, gw2t + (size_t)l * NH * HDIM, gat_b + (size_t)l * HDIM, y_bf,
            N_NODES, HDIM, NH);
        if (l < NLAYERS - 1) {
            ln_residual<true, false><<<N_NODES / 4, 256, 0, stream>>>(
                y_bf, ln_g + (size_t)l * HDIM, ln_b + (size_t)l * HDIM, x_bf,
                ws_s + (size_t)(l + 1) * 4 * HDIM, ws_d + (size_t)(l + 1) * 4 * HDIM,
                a_s, a_d, nullptr);
        } else {
            ln_residual<false, true><<<N_NODES / 4, 256, 0, stream>>>(
                y_bf, ln_g + (size_t)l * HDIM, ln_b + (size_t)l * HDIM, x_bf,
                nullptr, nullptr, nullptr, nullptr, out + 4 * N_NODES);
        }
    }

    gemm_head<<<GRID_HEAD, 256, 0, stream>>>(
        x_bf, hw1t, head_b1, N_NODES, 512, HDIM, head_w2, head_b2, out);
}